// Round 5
// baseline (959.158 us; speedup 1.0000x reference)
//
#include <hip/hip_runtime.h>
#include <hip/hip_bf16.h>

typedef __hip_bfloat16 bf16;
typedef __attribute__((ext_vector_type(8))) __bf16 bf16x8;
typedef __attribute__((ext_vector_type(4))) float f32x4;

typedef const __attribute__((address_space(1))) void cg_void;
typedef __attribute__((address_space(3))) void lds_void;

__device__ inline float b2f(bf16 v) { return __bfloat162float(v); }
__device__ inline bf16 f2b(float v) { return __float2bfloat16(v); }
__device__ inline float ldf(const float* p) { return *p; }
__device__ inline float ldf(const bf16* p) { return __bfloat162float(*p); }

#define BKK 32

// ---------------------------------------------------------------------------
// Batched GEMM: C[z] = A[z] (M x K, row-major lda) * Bt[z]^T (Bt: N x K rows,
// ldb). Per-z offsets: (z/zdiv)*Hi + (z%zdiv)*Lo for A, B, C independently.
// BM=128 fixed; BN_ in {128, 64}. global_load_lds (width 16) staging.
// XCD-aware bijective block swizzle (T1) when gridDim.x*y % 8 == 0.
// ---------------------------------------------------------------------------
template<int BN_, bool BIAS, bool RELU, bool OUT_BF16>
__global__ __launch_bounds__(256) void gemm_bt(
    const bf16* __restrict__ A, const bf16* __restrict__ Bt, void* __restrict__ Cout,
    const float* __restrict__ bias,
    int M, int N, int K, int lda, int ldb, int ldc,
    long aHi, long aLo, long bHi, long bLo, long cHi, long cLo, int zdiv)
{
  alignas(16) __shared__ bf16 As[128 * BKK];
  alignas(16) __shared__ bf16 Bs[BN_ * BKK];
  const int t = threadIdx.x;
  const int l = t & 63;
  const int w = t >> 6;
  const int z = blockIdx.z;
  const int zq = z / zdiv, zr = z % zdiv;
  A += (long)zq * aHi + (long)zr * aLo;
  Bt += (long)zq * bHi + (long)zr * bLo;
  const long cbase = (long)zq * cHi + (long)zr * cLo;

  // T1: XCD-aware swizzle — blocks resident on one XCD get contiguous tiles
  const int gx = gridDim.x;
  int bid = blockIdx.y * gx + blockIdx.x;
  const int nwg = gx * gridDim.y;
  if ((nwg & 7) == 0)
    bid = (bid & 7) * (nwg >> 3) + (bid >> 3);
  const int m0 = (bid % gx) * 128;
  const int n0 = (bid / gx) * BN_;

  constexpr int NJ = BN_ / 32;
  f32x4 acc[4][NJ] = {};

  const int r0 = t >> 2;
  const int kc = (t & 3) * 8;
  const bf16* aP0 = A + (long)(m0 + r0) * lda + kc;
  const bf16* aP1 = aP0 + (long)64 * lda;
  bf16* aD0 = As + t * 8;
  bf16* aD1 = As + (t + 256) * 8;
  const bf16* bP0 = Bt + (long)(n0 + r0) * ldb + kc;
  bf16* bD0 = Bs + t * 8;
  const bf16* bP1 = bP0 + (long)64 * ldb;
  bf16* bD1 = Bs + (t + 256) * 8;

  const int fr = l & 15;
  const int fk = (l >> 4) * 8;
  const int aRow = (w >> 1) * 64 + fr;
  const int bRow = (w & 1) * (BN_ / 2) + fr;

  for (int kt = 0; kt < K; kt += BKK) {
    __builtin_amdgcn_global_load_lds((cg_void*)(aP0 + kt), (lds_void*)aD0, 16, 0, 0);
    __builtin_amdgcn_global_load_lds((cg_void*)(aP1 + kt), (lds_void*)aD1, 16, 0, 0);
    __builtin_amdgcn_global_load_lds((cg_void*)(bP0 + kt), (lds_void*)bD0, 16, 0, 0);
    if constexpr (BN_ == 128)
      __builtin_amdgcn_global_load_lds((cg_void*)(bP1 + kt), (lds_void*)bD1, 16, 0, 0);
    __syncthreads();
    bf16x8 af[4], bv[NJ];
#pragma unroll
    for (int i = 0; i < 4; ++i)
      af[i] = *(const bf16x8*)(As + (aRow + i * 16) * BKK + fk);
#pragma unroll
    for (int j = 0; j < NJ; ++j)
      bv[j] = *(const bf16x8*)(Bs + (bRow + j * 16) * BKK + fk);
#pragma unroll
    for (int i = 0; i < 4; ++i)
#pragma unroll
      for (int j = 0; j < NJ; ++j)
        acc[i][j] = __builtin_amdgcn_mfma_f32_16x16x32_bf16(af[i], bv[j], acc[i][j], 0, 0, 0);
    __syncthreads();
  }

  float* cf = (float*)Cout;
  bf16* cb = (bf16*)Cout;
#pragma unroll
  for (int i = 0; i < 4; ++i) {
    const int mb = m0 + (w >> 1) * 64 + i * 16 + ((l >> 4) << 2);
#pragma unroll
    for (int j = 0; j < NJ; ++j) {
      const int nc = n0 + (w & 1) * (BN_ / 2) + j * 16 + fr;
      const float bvv = BIAS ? bias[nc] : 0.f;
#pragma unroll
      for (int r = 0; r < 4; ++r) {
        const int m = mb + r;
        const long off = cbase + (long)m * ldc + nc;
        float vv = acc[i][j][r] + bvv;
        if (RELU) vv = fmaxf(vv, 0.f);
        if (OUT_BF16) cb[off] = f2b(vv);
        else cf[off] = vv;
      }
    }
  }
}

template<int BN_, bool B_, bool R_, bool O_>
static inline void gemmL(hipStream_t st, int M, int N, int K,
                         const bf16* A, int lda, long aHi, long aLo,
                         const bf16* Bt, int ldb, long bHi, long bLo,
                         void* C, int ldc, long cHi, long cLo,
                         int zdiv, int nz, const float* bias)
{
  dim3 g(M / 128, N / BN_, nz);
  gemm_bt<BN_, B_, R_, O_><<<g, dim3(256), 0, st>>>(
      A, Bt, C, bias, M, N, K, lda, ldb, ldc, aHi, aLo, bHi, bLo, cHi, cLo, zdiv);
}

// ---------------------------------------------------------------------------
template<typename ST>
__global__ __launch_bounds__(256) void transpose_to_bf16(
    const ST* __restrict__ in, bf16* __restrict__ out, int R, int C, long sIn, long sOut)
{
  __shared__ bf16 tile[32][33];
  const int z = blockIdx.z;
  in += (long)z * sIn;
  out += (long)z * sOut;
  const int tx = threadIdx.x & 31, ty = threadIdx.x >> 5;
  const int c0 = blockIdx.x * 32, r0 = blockIdx.y * 32;
#pragma unroll
  for (int i = 0; i < 4; ++i)
    tile[ty + i * 8][tx] = f2b(ldf(in + (long)(r0 + ty + i * 8) * C + c0 + tx));
  __syncthreads();
#pragma unroll
  for (int i = 0; i < 4; ++i)
    out[(long)(c0 + ty + i * 8) * R + r0 + tx] = tile[tx][ty + i * 8];
}

__global__ __launch_bounds__(256) void cast4_k(
    const float* __restrict__ in, bf16* __restrict__ out, long n4)
{
  long i = (long)blockIdx.x * 256 + threadIdx.x;
  const long st = (long)gridDim.x * 256;
  for (; i < n4; i += st) {
    const float4 v = ((const float4*)in)[i];
    bf16* o = out + i * 4;
    o[0] = f2b(v.x); o[1] = f2b(v.y); o[2] = f2b(v.z); o[3] = f2b(v.w);
  }
}

// 4 independent f32->bf16 casts in one launch (blockIdx.y selects matrix)
__global__ __launch_bounds__(256) void cast4x4_k(
    const float* __restrict__ p0, const float* __restrict__ p1,
    const float* __restrict__ p2, const float* __restrict__ p3,
    bf16* __restrict__ o0, bf16* __restrict__ o1,
    bf16* __restrict__ o2, bf16* __restrict__ o3, long n4)
{
  const float* in; bf16* out;
  switch (blockIdx.y) {
    case 0: in = p0; out = o0; break;
    case 1: in = p1; out = o1; break;
    case 2: in = p2; out = o2; break;
    default: in = p3; out = o3; break;
  }
  long i = (long)blockIdx.x * 256 + threadIdx.x;
  const long st = (long)gridDim.x * 256;
  for (; i < n4; i += st) {
    const float4 v = ((const float4*)in)[i];
    bf16* o = out + i * 4;
    o[0] = f2b(v.x); o[1] = f2b(v.y); o[2] = f2b(v.z); o[3] = f2b(v.w);
  }
}

__global__ __launch_bounds__(256) void fill_sentinel(float* __restrict__ out, long n)
{
  long i = (long)blockIdx.x * 256 + threadIdx.x;
  const long st = (long)gridDim.x * 256;
  for (; i < n; i += st) out[i] = 1.0e6f;
}

// in-place softmax over 1024-wide rows of bf16 scores; arg = (S + v[t]) * scale
__global__ __launch_bounds__(256) void softmax_rows(
    bf16* __restrict__ S, const float* __restrict__ v, float scale, int causal)
{
  const int r = blockIdx.x * 4 + (threadIdx.x >> 6);
  const int l = threadIdx.x & 63;
  const int zl = r >> 10, s = r & 1023;
  bf16* row = S + (long)r * 1024;
  const float* vp = v + (zl >> 2) * 4096 + (zl & 3) * 1024;
  const int t0 = l * 16;
  bf16x8* rp = (bf16x8*)(row + t0);
  const bf16x8 a0 = rp[0], a1 = rp[1];
  float xx[16];
#pragma unroll
  for (int j = 0; j < 8; ++j) { xx[j] = (float)a0[j]; xx[8 + j] = (float)a1[j]; }
  float mx = -3.4e38f;
#pragma unroll
  for (int k = 0; k < 16; ++k) {
    const int tt = t0 + k;
    float val = (xx[k] + vp[tt]) * scale;
    if (causal && tt > s) val = -3.4e38f;
    xx[k] = val;
    mx = fmaxf(mx, val);
  }
#pragma unroll
  for (int d = 1; d < 64; d <<= 1) mx = fmaxf(mx, __shfl_xor(mx, d));
  float sum = 0.f;
#pragma unroll
  for (int k = 0; k < 16; ++k) {
    const float e = (xx[k] > -1e37f) ? __expf(xx[k] - mx) : 0.f;
    xx[k] = e;
    sum += e;
  }
#pragma unroll
  for (int d = 1; d < 64; d <<= 1) sum += __shfl_xor(sum, d);
  const float inv = 1.f / sum;
  bf16x8 r0v, r1v;
#pragma unroll
  for (int j = 0; j < 8; ++j) {
    r0v[j] = (__bf16)(xx[j] * inv);
    r1v[j] = (__bf16)(xx[8 + j] * inv);
  }
  rp[0] = r0v;
  rp[1] = r1v;
}

// fused: sum split-K partials + beff + residual -> LayerNorm -> bf16/fp32 out
__global__ __launch_bounds__(256) void ln_fused(
    const float* __restrict__ parts, long zstride, int nz,
    const float* __restrict__ beff, const float* __restrict__ resF,
    const bf16* __restrict__ resB, const float* __restrict__ g,
    const float* __restrict__ b, bf16* __restrict__ outB, float* __restrict__ outF)
{
  const int m = blockIdx.x * 4 + (threadIdx.x >> 6);
  const int l = threadIdx.x & 63;
  float vv[8];
  float s = 0.f;
#pragma unroll
  for (int i = 0; i < 8; ++i) {
    const int c = i * 64 + l;
    float acc = beff[c];
    if (resF) acc += resF[(long)m * 512 + c];
    else acc += b2f(resB[(long)m * 512 + c]);
    for (int zz = 0; zz < nz; ++zz) acc += parts[zz * zstride + (long)m * 512 + c];
    vv[i] = acc;
    s += acc;
  }
#pragma unroll
  for (int d = 1; d < 64; d <<= 1) s += __shfl_xor(s, d);
  const float mean = s * (1.f / 512.f);
  float vs = 0.f;
#pragma unroll
  for (int i = 0; i < 8; ++i) { const float dv = vv[i] - mean; vs += dv * dv; }
#pragma unroll
  for (int d = 1; d < 64; d <<= 1) vs += __shfl_xor(vs, d);
  const float rstd = rsqrtf(vs * (1.f / 512.f) + 1e-5f);
#pragma unroll
  for (int i = 0; i < 8; ++i) {
    const int c = i * 64 + l;
    const float y = (vv[i] - mean) * rstd * g[c] + b[c];
    if (outB) outB[(long)m * 512 + c] = f2b(y);
    if (outF) outF[(long)m * 512 + c] = y;
  }
}

// ---- parallel bias-fold kernels ----
__global__ void beff_init_k(const float* __restrict__ bf_, float* __restrict__ beff)
{
  const int e = blockIdx.x * 256 + threadIdx.x;
  if (e < 512) beff[e] = bf_[e];
}

__global__ __launch_bounds__(256) void beff_wf_k(
    const float* __restrict__ bo, const float* __restrict__ wf, float* __restrict__ beff)
{
  const int t = threadIdx.x;
  const int r0 = blockIdx.x * 128;
  float s0 = 0.f, s1 = 0.f;
  for (int r = 0; r < 128; ++r) {
    const float bb = bo[r0 + r];
    const float* row = wf + (long)(r0 + r) * 512;
    s0 += bb * row[t];
    s1 += bb * row[t + 256];
  }
  atomicAdd(&beff[t], s0);
  atomicAdd(&beff[t + 256], s1);
}

__global__ __launch_bounds__(256) void beff_w2_k(
    const float* __restrict__ bv, const bf16* __restrict__ W2t, float* __restrict__ beff)
{
  const int e = blockIdx.x * 4 + (threadIdx.x >> 6);
  const int l = threadIdx.x & 63;
  const bf16* row = W2t + (long)e * 4096;
  float s = 0.f;
#pragma unroll
  for (int j = 0; j < 8; ++j) {
    const int hf = j * 512 + l * 8;
    const bf16x8 wv = *(const bf16x8*)(row + hf);
    const float4 b0 = *(const float4*)(bv + hf);
    const float4 b1 = *(const float4*)(bv + hf + 4);
    s += (float)wv[0] * b0.x + (float)wv[1] * b0.y + (float)wv[2] * b0.z + (float)wv[3] * b0.w;
    s += (float)wv[4] * b1.x + (float)wv[5] * b1.y + (float)wv[6] * b1.z + (float)wv[7] * b1.w;
  }
#pragma unroll
  for (int d = 1; d < 64; d <<= 1) s += __shfl_xor(s, d);
  if (l == 0) atomicAdd(&beff[e], s);
}

__global__ __launch_bounds__(256) void wkbq_k(
    const float* __restrict__ wk, const float* __restrict__ bq, float* __restrict__ o)
{
  const int id = blockIdx.x * 4 + (threadIdx.x >> 6);
  const int l = threadIdx.x & 63;
  const int h = id >> 9, d = id & 511;
  const float* wp = wk + (long)h * 262144 + (long)d * 512 + l * 8;
  const float* bp = bq + h * 512 + l * 8;
  float s = 0.f;
#pragma unroll
  for (int j = 0; j < 2; ++j) {
    const float4 a = *(const float4*)(wp + j * 4);
    const float4 b = *(const float4*)(bp + j * 4);
    s += a.x * b.x + a.y * b.y + a.z * b.z + a.w * b.w;
  }
#pragma unroll
  for (int dd = 1; dd < 64; dd <<= 1) s += __shfl_xor(s, dd);
  if (l == 0) o[id] = s;
}

__global__ __launch_bounds__(256) void rank1_v(
    const bf16* __restrict__ kvB, const float* __restrict__ wkbq, float* __restrict__ v)
{
  const int m = blockIdx.x * 4 + (threadIdx.x >> 6);
  const int l = threadIdx.x & 63;
  const bf16x8 row = *(const bf16x8*)(kvB + (long)m * 512 + l * 8);
  float rf[8];
#pragma unroll
  for (int j = 0; j < 8; ++j) rf[j] = (float)row[j];
  for (int h = 0; h < 8; ++h) {
    const float* wp = wkbq + h * 512 + l * 8;
    float p = 0.f;
#pragma unroll
    for (int j = 0; j < 8; ++j) p += rf[j] * wp[j];
#pragma unroll
    for (int d = 1; d < 64; d <<= 1) p += __shfl_xor(p, d);
    if (l == 0) v[(long)h * 4096 + m] = p;
  }
}

// ---------------------------------------------------------------------------
extern "C" void kernel_launch(void* const* d_in, const int* in_sizes, int n_in,
                              void* d_out, int out_size, void* d_ws, size_t ws_size,
                              hipStream_t stream)
{
  (void)in_sizes; (void)n_in;
  const float* x = (const float*)d_in[0];
  const float* enc = (const float*)d_in[1];
  const float* ln_g[3] = {(const float*)d_in[22], (const float*)d_in[24], (const float*)d_in[26]};
  const float* ln_b[3] = {(const float*)d_in[23], (const float*)d_in[25], (const float*)d_in[27]};
  const float* fc1_w = (const float*)d_in[28];
  const float* fc1_b = (const float*)d_in[29];
  const float* fc2_w = (const float*)d_in[30];
  const float* fc2_b = (const float*)d_in[31];

  const float scale = 0.044194173824159216f;  // 1/sqrt(512)
  char* base = (char*)d_ws;
  const long MB = 1024 * 1024;

  // ---- layout (193 MB; ws is 256 MiB) ----
  bf16* Xb    = (bf16*)(base + 0 * MB);
  bf16* Eb    = (bf16*)(base + 4 * MB);
  bf16* x1b   = (bf16*)(base + 8 * MB);
  bf16* x2b   = (bf16*)(base + 12 * MB);
  bf16* fc1T  = (bf16*)(base + 16 * MB);
  bf16* fc2T  = (bf16*)(base + 18 * MB);
  float* vbuf = (float*)(base + 20 * MB);
  float* wkbq = (float*)(base + 20 * MB + 256 * 1024);
  float* beff = (float*)(base + 20 * MB + 512 * 1024);
  bf16* XT    = (bf16*)(base + 21 * MB);
  bf16* WqkT  = (bf16*)(base + 25 * MB);
  bf16* W3cat = (bf16*)(base + 29 * MB);
  bf16* T     = (bf16*)(base + 33 * MB);     // 32 MB [4096,4096]
  float* parts = (float*)(base + 65 * MB);   // 32 MB [4][4096,512] f32
  bf16* scores = (bf16*)(base + 97 * MB);    // 64 MB [32][1024][1024]
  bf16* AX    = (bf16*)(base + 161 * MB);    // 32 MB [4096,4096]
  // prep scratch + FFN hidden alias the scores region (dead during prep/FFN)
  bf16* wqB   = (bf16*)(base + 97 * MB);
  bf16* wkB   = (bf16*)(base + 101 * MB);
  bf16* wvB   = (bf16*)(base + 105 * MB);
  bf16* woB   = (bf16*)(base + 109 * MB);
  bf16* wfT   = (bf16*)(base + 113 * MB);
  bf16* W2t   = (bf16*)(base + 117 * MB);
  bf16* Hb    = (bf16*)(base + 97 * MB);     // 16 MB [4096,2048]

  if (ws_size < (size_t)(193 * MB)) {
    fill_sentinel<<<dim3(2048), dim3(256), 0, stream>>>((float*)d_out, (long)out_size);
    return;
  }

  // ---- global prep ----
  cast4_k<<<dim3(512), dim3(256), 0, stream>>>(x, Xb, 4096L * 512 / 4);
  cast4_k<<<dim3(512), dim3(256), 0, stream>>>(enc, Eb, 4096L * 512 / 4);
  transpose_to_bf16<float><<<dim3(64, 16, 1), dim3(256), 0, stream>>>(fc1_w, fc1T, 512, 2048, 0, 0);
  transpose_to_bf16<float><<<dim3(16, 64, 1), dim3(256), 0, stream>>>(fc2_w, fc2T, 2048, 512, 0, 0);

  auto run_attn = [&](int ib, const bf16* qB, const bf16* kvB,
                      const float* resF, const bf16* resB, int causal,
                      const float* lg, const float* lb, bf16* outB) {
    const float* wq = (const float*)d_in[ib + 0];
    const float* bq = (const float*)d_in[ib + 1];
    const float* wk = (const float*)d_in[ib + 2];
    const float* wv = (const float*)d_in[ib + 4];
    const float* bv = (const float*)d_in[ib + 5];
    const float* wo = (const float*)d_in[ib + 6];
    const float* bo = (const float*)d_in[ib + 7];
    const float* wf = (const float*)d_in[ib + 8];
    const float* bfv = (const float*)d_in[ib + 9];

    cast4x4_k<<<dim3(512, 4), dim3(256), 0, stream>>>(
        wq, wk, wv, wo, wqB, wkB, wvB, woB, 2097152 / 4);
    transpose_to_bf16<float><<<dim3(16, 128, 1), dim3(256), 0, stream>>>(wf, wfT, 4096, 512, 0, 0);
    // W2t[e][h*512+f] = sum_g wfT[e][h*512+g] * wo[h][f][g]
    gemmL<64, false, false, true>(stream, 512, 512, 512,
        wfT, 4096, 512, 0, woB, 512, 262144, 0, W2t, 4096, 512, 0, 1, 8, nullptr);
    beff_init_k<<<dim3(2), dim3(256), 0, stream>>>(bfv, beff);
    beff_wf_k<<<dim3(32), dim3(256), 0, stream>>>(bo, wf, beff);
    beff_w2_k<<<dim3(128), dim3(256), 0, stream>>>(bv, W2t, beff);
    // WqkT[h*512+d2][d1] = sum_f wk[h,d2,f] * wq[h,d1,f]
    gemmL<64, false, false, true>(stream, 512, 512, 512,
        wkB, 512, 262144, 0, wqB, 512, 262144, 0, WqkT, 512, 262144, 0, 1, 8, nullptr);
    // W3cat[e][h*512+d] = sum_f W2t[e][h*512+f] * wv[h,d,f]
    gemmL<64, false, false, true>(stream, 512, 512, 512,
        W2t, 4096, 512, 0, wvB, 512, 262144, 0, W3cat, 4096, 512, 0, 1, 8, nullptr);
    wkbq_k<<<dim3(1024), dim3(256), 0, stream>>>(wk, bq, wkbq);
    rank1_v<<<dim3(1024), dim3(256), 0, stream>>>(kvB, wkbq, vbuf);
    transpose_to_bf16<bf16><<<dim3(16, 32, 4), dim3(256), 0, stream>>>(
        kvB, XT, 1024, 512, 524288, 524288);
    // T = qB @ Wqk  [4096, 4096]
    gemmL<128, false, false, true>(stream, 4096, 4096, 512,
        qB, 512, 0, 0, WqkT, 512, 0, 0, T, 4096, 0, 0, 1, 1, nullptr);

    // scores for ALL 32 (h,b): z/4 = head (A col, C hi), z%4 = batch
    gemmL<128, false, false, true>(stream, 1024, 1024, 512,
        T, 4096, 512, 4194304,
        kvB, 512, 0, 524288,
        scores, 1024, 4194304, 1048576, 4, 32, nullptr);
    softmax_rows<<<dim3(8192), dim3(256), 0, stream>>>(scores, vbuf, scale, causal);
    // AX = P @ Xk for all 32
    gemmL<64, false, false, true>(stream, 1024, 512, 1024,
        scores, 1024, 4194304, 1048576,
        XT, 1024, 0, 524288,
        AX, 4096, 512, 4194304, 4, 32, nullptr);
    // out partials = AX @ W3cat^T (split-K = 4)
    gemmL<64, false, false, false>(stream, 4096, 512, 1024,
        AX, 4096, 1024, 0, W3cat, 4096, 1024, 0,
        parts, 512, 2097152, 0, 1, 4, nullptr);
    ln_fused<<<dim3(1024), dim3(256), 0, stream>>>(
        parts, 2097152, 4, beff, resF, resB, lg, lb, outB, nullptr);
  };

  run_attn(2, Xb, Xb, x, nullptr, 1, ln_g[0], ln_b[0], x1b);
  run_attn(12, x1b, Eb, nullptr, x1b, 0, ln_g[1], ln_b[1], x2b);

  // ---- FFN ----
  gemmL<128, true, true, true>(stream, 4096, 2048, 512,
      x2b, 512, 0, 0, fc1T, 512, 0, 0, Hb, 2048, 0, 0, 1, 1, fc1_b);
  gemmL<64, false, false, false>(stream, 4096, 512, 512,
      Hb, 2048, 512, 0, fc2T, 2048, 512, 0, parts, 512, 2097152, 0, 1, 4, nullptr);
  ln_fused<<<dim3(1024), dim3(256), 0, stream>>>(
      parts, 2097152, 4, fc2_b, nullptr, x2b, ln_g[2], ln_b[2], nullptr, (float*)d_out);
}

// Round 6
// 797.246 us; speedup vs baseline: 1.2031x; 1.2031x over previous
//
#include <hip/hip_runtime.h>
#include <hip/hip_bf16.h>

typedef __hip_bfloat16 bf16;
typedef __attribute__((ext_vector_type(8))) __bf16 bf16x8;
typedef __attribute__((ext_vector_type(4))) float f32x4;

typedef const __attribute__((address_space(1))) void cg_void;
typedef __attribute__((address_space(3))) void lds_void;

__device__ inline float b2f(bf16 v) { return __bfloat162float(v); }
__device__ inline bf16 f2b(float v) { return __float2bfloat16(v); }
__device__ inline float ldf(const float* p) { return *p; }
__device__ inline float ldf(const bf16* p) { return __bfloat162float(*p); }

#define BKK 32

template<int N> __device__ __forceinline__ void wait_vm() {
  if constexpr (N == 0) asm volatile("s_waitcnt vmcnt(0)" ::: "memory");
  else if constexpr (N == 3) asm volatile("s_waitcnt vmcnt(3)" ::: "memory");
  else asm volatile("s_waitcnt vmcnt(4)" ::: "memory");
}

// ---------------------------------------------------------------------------
// Batched GEMM: C[z] = A[z] (M x K, row-major lda) * Bt[z]^T (Bt: N x K rows,
// ldb). Per-z offsets: (z/zdiv)*Hi + (z%zdiv)*Lo for A, B, C independently.
// Depth-3 pipelined global_load_lds staging with counted vmcnt (T3+T4 min);
// flat-grid XCD chunking (each XCD owns a contiguous range of (z,n,m) tiles).
// ---------------------------------------------------------------------------
template<int BN_, bool BIAS, bool RELU, bool OUT_BF16>
__global__ __launch_bounds__(256) void gemm_bt(
    const bf16* __restrict__ A, const bf16* __restrict__ Bt, void* __restrict__ Cout,
    const float* __restrict__ bias,
    int M, int N, int K, int lda, int ldb, int ldc,
    long aHi, long aLo, long bHi, long bLo, long cHi, long cLo, int zdiv)
{
  constexpr int NL = (BN_ == 128) ? 4 : 3;   // global_load_lds instrs per tile
  alignas(16) __shared__ bf16 As[3][128 * BKK];
  alignas(16) __shared__ bf16 Bs[3][BN_ * BKK];
  const int t = threadIdx.x;
  const int l = t & 63;
  const int w = t >> 6;

  // flat-grid decode; XCD k gets flat ids [k*total/8, (k+1)*total/8)
  const int gx = gridDim.x;
  const long gxy = (long)gx * gridDim.y;
  long flat = (long)blockIdx.z * gxy + (long)blockIdx.y * gx + blockIdx.x;
  const long total = gxy * gridDim.z;
  if ((total & 7) == 0) flat = (flat & 7) * (total >> 3) + (flat >> 3);
  const int z = (int)(flat / gxy);
  const int rem = (int)(flat % gxy);
  const int m0 = (rem % gx) * 128;
  const int n0 = (rem / gx) * BN_;

  const int zq = z / zdiv, zr = z % zdiv;
  A += (long)zq * aHi + (long)zr * aLo;
  Bt += (long)zq * bHi + (long)zr * bLo;
  const long cbase = (long)zq * cHi + (long)zr * cLo;

  constexpr int NJ = BN_ / 32;
  f32x4 acc[4][NJ] = {};

  const int r0 = t >> 2;
  const int kc = (t & 3) * 8;
  const bf16* aP0 = A + (long)(m0 + r0) * lda + kc;
  const bf16* aP1 = aP0 + (long)64 * lda;
  const bf16* bP0 = Bt + (long)(n0 + r0) * ldb + kc;
  const bf16* bP1 = bP0 + (long)64 * ldb;

  const int fr = l & 15;
  const int fk = (l >> 4) * 8;
  const int aRow = (w >> 1) * 64 + fr;
  const int bRow = (w & 1) * (BN_ / 2) + fr;

  const int nt = K >> 5;

  auto stage = [&](int tt, int bi) {
    const long kt = (long)tt * BKK;
    __builtin_amdgcn_global_load_lds((cg_void*)(aP0 + kt), (lds_void*)(&As[bi][t * 8]), 16, 0, 0);
    __builtin_amdgcn_global_load_lds((cg_void*)(aP1 + kt), (lds_void*)(&As[bi][(t + 256) * 8]), 16, 0, 0);
    __builtin_amdgcn_global_load_lds((cg_void*)(bP0 + kt), (lds_void*)(&Bs[bi][t * 8]), 16, 0, 0);
    if constexpr (BN_ == 128)
      __builtin_amdgcn_global_load_lds((cg_void*)(bP1 + kt), (lds_void*)(&Bs[bi][(t + 256) * 8]), 16, 0, 0);
  };

  // prologue: tiles 0,1 in flight; wait tile 0 (allow tile 1 outstanding)
  stage(0, 0);
  stage(1, 1);
  wait_vm<NL>();
  __builtin_amdgcn_s_barrier();

  int bi = 0;
  for (int tt = 0; tt < nt; ++tt) {
    if (tt + 2 < nt) stage(tt + 2, bi == 0 ? 2 : bi - 1);   // buf (bi+2)%3
    bf16x8 af[4], bv[NJ];
#pragma unroll
    for (int i = 0; i < 4; ++i)
      af[i] = *(const bf16x8*)(&As[bi][(aRow + i * 16) * BKK + fk]);
#pragma unroll
    for (int j = 0; j < NJ; ++j)
      bv[j] = *(const bf16x8*)(&Bs[bi][(bRow + j * 16) * BKK + fk]);
#pragma unroll
    for (int i = 0; i < 4; ++i)
#pragma unroll
      for (int j = 0; j < NJ; ++j)
        acc[i][j] = __builtin_amdgcn_mfma_f32_16x16x32_bf16(af[i], bv[j], acc[i][j], 0, 0, 0);
    if (tt + 1 < nt) {
      if (tt + 2 < nt) wait_vm<NL>();   // next tile landed; tile t+2 stays in flight
      else wait_vm<0>();                // draining: only t+1 outstanding
      __builtin_amdgcn_s_barrier();
    }
    bi = (bi == 2) ? 0 : bi + 1;
  }

  float* cf = (float*)Cout;
  bf16* cb = (bf16*)Cout;
#pragma unroll
  for (int i = 0; i < 4; ++i) {
    const int mb = m0 + (w >> 1) * 64 + i * 16 + ((l >> 4) << 2);
#pragma unroll
    for (int j = 0; j < NJ; ++j) {
      const int nc = n0 + (w & 1) * (BN_ / 2) + j * 16 + fr;
      const float bvv = BIAS ? bias[nc] : 0.f;
#pragma unroll
      for (int r = 0; r < 4; ++r) {
        const int m = mb + r;
        const long off = cbase + (long)m * ldc + nc;
        float vv = acc[i][j][r] + bvv;
        if (RELU) vv = fmaxf(vv, 0.f);
        if (OUT_BF16) cb[off] = f2b(vv);
        else cf[off] = vv;
      }
    }
  }
}

template<int BN_, bool B_, bool R_, bool O_>
static inline void gemmL(hipStream_t st, int M, int N, int K,
                         const bf16* A, int lda, long aHi, long aLo,
                         const bf16* Bt, int ldb, long bHi, long bLo,
                         void* C, int ldc, long cHi, long cLo,
                         int zdiv, int nz, const float* bias)
{
  dim3 g(M / 128, N / BN_, nz);
  gemm_bt<BN_, B_, R_, O_><<<g, dim3(256), 0, st>>>(
      A, Bt, C, bias, M, N, K, lda, ldb, ldc, aHi, aLo, bHi, bLo, cHi, cLo, zdiv);
}

// ---------------------------------------------------------------------------
template<typename ST>
__global__ __launch_bounds__(256) void transpose_to_bf16(
    const ST* __restrict__ in, bf16* __restrict__ out, int R, int C, long sIn, long sOut)
{
  __shared__ bf16 tile[32][33];
  const int z = blockIdx.z;
  in += (long)z * sIn;
  out += (long)z * sOut;
  const int tx = threadIdx.x & 31, ty = threadIdx.x >> 5;
  const int c0 = blockIdx.x * 32, r0 = blockIdx.y * 32;
#pragma unroll
  for (int i = 0; i < 4; ++i)
    tile[ty + i * 8][tx] = f2b(ldf(in + (long)(r0 + ty + i * 8) * C + c0 + tx));
  __syncthreads();
#pragma unroll
  for (int i = 0; i < 4; ++i)
    out[(long)(c0 + ty + i * 8) * R + r0 + tx] = tile[tx][ty + i * 8];
}

__global__ __launch_bounds__(256) void cast4_k(
    const float* __restrict__ in, bf16* __restrict__ out, long n4)
{
  long i = (long)blockIdx.x * 256 + threadIdx.x;
  const long st = (long)gridDim.x * 256;
  for (; i < n4; i += st) {
    const float4 v = ((const float4*)in)[i];
    bf16* o = out + i * 4;
    o[0] = f2b(v.x); o[1] = f2b(v.y); o[2] = f2b(v.z); o[3] = f2b(v.w);
  }
}

// 4 independent f32->bf16 casts in one launch (blockIdx.y selects matrix)
__global__ __launch_bounds__(256) void cast4x4_k(
    const float* __restrict__ p0, const float* __restrict__ p1,
    const float* __restrict__ p2, const float* __restrict__ p3,
    bf16* __restrict__ o0, bf16* __restrict__ o1,
    bf16* __restrict__ o2, bf16* __restrict__ o3, long n4)
{
  const float* in; bf16* out;
  switch (blockIdx.y) {
    case 0: in = p0; out = o0; break;
    case 1: in = p1; out = o1; break;
    case 2: in = p2; out = o2; break;
    default: in = p3; out = o3; break;
  }
  long i = (long)blockIdx.x * 256 + threadIdx.x;
  const long st = (long)gridDim.x * 256;
  for (; i < n4; i += st) {
    const float4 v = ((const float4*)in)[i];
    bf16* o = out + i * 4;
    o[0] = f2b(v.x); o[1] = f2b(v.y); o[2] = f2b(v.z); o[3] = f2b(v.w);
  }
}

__global__ __launch_bounds__(256) void fill_sentinel(float* __restrict__ out, long n)
{
  long i = (long)blockIdx.x * 256 + threadIdx.x;
  const long st = (long)gridDim.x * 256;
  for (; i < n; i += st) out[i] = 1.0e6f;
}

// in-place softmax over 1024-wide rows of bf16 scores; arg = (S + v[t]) * scale
__global__ __launch_bounds__(256) void softmax_rows(
    bf16* __restrict__ S, const float* __restrict__ v, float scale, int causal)
{
  const int r = blockIdx.x * 4 + (threadIdx.x >> 6);
  const int l = threadIdx.x & 63;
  const int zl = r >> 10, s = r & 1023;
  bf16* row = S + (long)r * 1024;
  const float* vp = v + (zl >> 2) * 4096 + (zl & 3) * 1024;
  const int t0 = l * 16;
  bf16x8* rp = (bf16x8*)(row + t0);
  const bf16x8 a0 = rp[0], a1 = rp[1];
  float xx[16];
#pragma unroll
  for (int j = 0; j < 8; ++j) { xx[j] = (float)a0[j]; xx[8 + j] = (float)a1[j]; }
  float mx = -3.4e38f;
#pragma unroll
  for (int k = 0; k < 16; ++k) {
    const int tt = t0 + k;
    float val = (xx[k] + vp[tt]) * scale;
    if (causal && tt > s) val = -3.4e38f;
    xx[k] = val;
    mx = fmaxf(mx, val);
  }
#pragma unroll
  for (int d = 1; d < 64; d <<= 1) mx = fmaxf(mx, __shfl_xor(mx, d));
  float sum = 0.f;
#pragma unroll
  for (int k = 0; k < 16; ++k) {
    const float e = (xx[k] > -1e37f) ? __expf(xx[k] - mx) : 0.f;
    xx[k] = e;
    sum += e;
  }
#pragma unroll
  for (int d = 1; d < 64; d <<= 1) sum += __shfl_xor(sum, d);
  const float inv = 1.f / sum;
  bf16x8 r0v, r1v;
#pragma unroll
  for (int j = 0; j < 8; ++j) {
    r0v[j] = (__bf16)(xx[j] * inv);
    r1v[j] = (__bf16)(xx[8 + j] * inv);
  }
  rp[0] = r0v;
  rp[1] = r1v;
}

// fused: sum split-K partials + beff + residual -> LayerNorm -> bf16/fp32 out
__global__ __launch_bounds__(256) void ln_fused(
    const float* __restrict__ parts, long zstride, int nz,
    const float* __restrict__ beff, const float* __restrict__ resF,
    const bf16* __restrict__ resB, const float* __restrict__ g,
    const float* __restrict__ b, bf16* __restrict__ outB, float* __restrict__ outF)
{
  const int m = blockIdx.x * 4 + (threadIdx.x >> 6);
  const int l = threadIdx.x & 63;
  float vv[8];
  float s = 0.f;
#pragma unroll
  for (int i = 0; i < 8; ++i) {
    const int c = i * 64 + l;
    float acc = beff[c];
    if (resF) acc += resF[(long)m * 512 + c];
    else acc += b2f(resB[(long)m * 512 + c]);
    for (int zz = 0; zz < nz; ++zz) acc += parts[zz * zstride + (long)m * 512 + c];
    vv[i] = acc;
    s += acc;
  }
#pragma unroll
  for (int d = 1; d < 64; d <<= 1) s += __shfl_xor(s, d);
  const float mean = s * (1.f / 512.f);
  float vs = 0.f;
#pragma unroll
  for (int i = 0; i < 8; ++i) { const float dv = vv[i] - mean; vs += dv * dv; }
#pragma unroll
  for (int d = 1; d < 64; d <<= 1) vs += __shfl_xor(vs, d);
  const float rstd = rsqrtf(vs * (1.f / 512.f) + 1e-5f);
#pragma unroll
  for (int i = 0; i < 8; ++i) {
    const int c = i * 64 + l;
    const float y = (vv[i] - mean) * rstd * g[c] + b[c];
    if (outB) outB[(long)m * 512 + c] = f2b(y);
    if (outF) outF[(long)m * 512 + c] = y;
  }
}

// ---- parallel bias-fold kernels ----
__global__ void beff_init_k(const float* __restrict__ bf_, float* __restrict__ beff)
{
  const int e = blockIdx.x * 256 + threadIdx.x;
  if (e < 512) beff[e] = bf_[e];
}

__global__ __launch_bounds__(256) void beff_wf_k(
    const float* __restrict__ bo, const float* __restrict__ wf, float* __restrict__ beff)
{
  const int t = threadIdx.x;
  const int r0 = blockIdx.x * 128;
  float s0 = 0.f, s1 = 0.f;
  for (int r = 0; r < 128; ++r) {
    const float bb = bo[r0 + r];
    const float* row = wf + (long)(r0 + r) * 512;
    s0 += bb * row[t];
    s1 += bb * row[t + 256];
  }
  atomicAdd(&beff[t], s0);
  atomicAdd(&beff[t + 256], s1);
}

__global__ __launch_bounds__(256) void beff_w2_k(
    const float* __restrict__ bv, const bf16* __restrict__ W2t, float* __restrict__ beff)
{
  const int e = blockIdx.x * 4 + (threadIdx.x >> 6);
  const int l = threadIdx.x & 63;
  const bf16* row = W2t + (long)e * 4096;
  float s = 0.f;
#pragma unroll
  for (int j = 0; j < 8; ++j) {
    const int hf = j * 512 + l * 8;
    const bf16x8 wv = *(const bf16x8*)(row + hf);
    const float4 b0 = *(const float4*)(bv + hf);
    const float4 b1 = *(const float4*)(bv + hf + 4);
    s += (float)wv[0] * b0.x + (float)wv[1] * b0.y + (float)wv[2] * b0.z + (float)wv[3] * b0.w;
    s += (float)wv[4] * b1.x + (float)wv[5] * b1.y + (float)wv[6] * b1.z + (float)wv[7] * b1.w;
  }
#pragma unroll
  for (int d = 1; d < 64; d <<= 1) s += __shfl_xor(s, d);
  if (l == 0) atomicAdd(&beff[e], s);
}

__global__ __launch_bounds__(256) void wkbq_k(
    const float* __restrict__ wk, const float* __restrict__ bq, float* __restrict__ o)
{
  const int id = blockIdx.x * 4 + (threadIdx.x >> 6);
  const int l = threadIdx.x & 63;
  const int h = id >> 9, d = id & 511;
  const float* wp = wk + (long)h * 262144 + (long)d * 512 + l * 8;
  const float* bp = bq + h * 512 + l * 8;
  float s = 0.f;
#pragma unroll
  for (int j = 0; j < 2; ++j) {
    const float4 a = *(const float4*)(wp + j * 4);
    const float4 b = *(const float4*)(bp + j * 4);
    s += a.x * b.x + a.y * b.y + a.z * b.z + a.w * b.w;
  }
#pragma unroll
  for (int dd = 1; dd < 64; dd <<= 1) s += __shfl_xor(s, dd);
  if (l == 0) o[id] = s;
}

__global__ __launch_bounds__(256) void rank1_v(
    const bf16* __restrict__ kvB, const float* __restrict__ wkbq, float* __restrict__ v)
{
  const int m = blockIdx.x * 4 + (threadIdx.x >> 6);
  const int l = threadIdx.x & 63;
  const bf16x8 row = *(const bf16x8*)(kvB + (long)m * 512 + l * 8);
  float rf[8];
#pragma unroll
  for (int j = 0; j < 8; ++j) rf[j] = (float)row[j];
  for (int h = 0; h < 8; ++h) {
    const float* wp = wkbq + h * 512 + l * 8;
    float p = 0.f;
#pragma unroll
    for (int j = 0; j < 8; ++j) p += rf[j] * wp[j];
#pragma unroll
    for (int d = 1; d < 64; d <<= 1) p += __shfl_xor(p, d);
    if (l == 0) v[(long)h * 4096 + m] = p;
  }
}

// ---------------------------------------------------------------------------
extern "C" void kernel_launch(void* const* d_in, const int* in_sizes, int n_in,
                              void* d_out, int out_size, void* d_ws, size_t ws_size,
                              hipStream_t stream)
{
  (void)in_sizes; (void)n_in;
  const float* x = (const float*)d_in[0];
  const float* enc = (const float*)d_in[1];
  const float* ln_g[3] = {(const float*)d_in[22], (const float*)d_in[24], (const float*)d_in[26]};
  const float* ln_b[3] = {(const float*)d_in[23], (const float*)d_in[25], (const float*)d_in[27]};
  const float* fc1_w = (const float*)d_in[28];
  const float* fc1_b = (const float*)d_in[29];
  const float* fc2_w = (const float*)d_in[30];
  const float* fc2_b = (const float*)d_in[31];

  const float scale = 0.044194173824159216f;  // 1/sqrt(512)
  char* base = (char*)d_ws;
  const long MB = 1024 * 1024;

  // ---- layout (193 MB; ws is 256 MiB) ----
  bf16* Xb    = (bf16*)(base + 0 * MB);
  bf16* Eb    = (bf16*)(base + 4 * MB);
  bf16* x1b   = (bf16*)(base + 8 * MB);
  bf16* x2b   = (bf16*)(base + 12 * MB);
  bf16* fc1T  = (bf16*)(base + 16 * MB);
  bf16* fc2T  = (bf16*)(base + 18 * MB);
  float* vbuf = (float*)(base + 20 * MB);
  float* wkbq = (float*)(base + 20 * MB + 256 * 1024);
  float* beff = (float*)(base + 20 * MB + 512 * 1024);
  bf16* XT    = (bf16*)(base + 21 * MB);
  bf16* WqkT  = (bf16*)(base + 25 * MB);
  bf16* W3cat = (bf16*)(base + 29 * MB);
  bf16* T     = (bf16*)(base + 33 * MB);     // 32 MB [4096,4096]
  float* parts = (float*)(base + 65 * MB);   // 32 MB [4][4096,512] f32
  bf16* scores = (bf16*)(base + 97 * MB);    // 64 MB [32][1024][1024]
  bf16* AX    = (bf16*)(base + 161 * MB);    // 32 MB [4096,4096]
  // prep scratch + FFN hidden alias the scores region (dead during prep/FFN)
  bf16* wqB   = (bf16*)(base + 97 * MB);
  bf16* wkB   = (bf16*)(base + 101 * MB);
  bf16* wvB   = (bf16*)(base + 105 * MB);
  bf16* woB   = (bf16*)(base + 109 * MB);
  bf16* wfT   = (bf16*)(base + 113 * MB);
  bf16* W2t   = (bf16*)(base + 117 * MB);
  bf16* Hb    = (bf16*)(base + 97 * MB);     // 16 MB [4096,2048]

  if (ws_size < (size_t)(193 * MB)) {
    fill_sentinel<<<dim3(2048), dim3(256), 0, stream>>>((float*)d_out, (long)out_size);
    return;
  }

  // ---- global prep ----
  cast4_k<<<dim3(512), dim3(256), 0, stream>>>(x, Xb, 4096L * 512 / 4);
  cast4_k<<<dim3(512), dim3(256), 0, stream>>>(enc, Eb, 4096L * 512 / 4);
  transpose_to_bf16<float><<<dim3(64, 16, 1), dim3(256), 0, stream>>>(fc1_w, fc1T, 512, 2048, 0, 0);
  transpose_to_bf16<float><<<dim3(16, 64, 1), dim3(256), 0, stream>>>(fc2_w, fc2T, 2048, 512, 0, 0);

  auto run_attn = [&](int ib, const bf16* qB, const bf16* kvB,
                      const float* resF, const bf16* resB, int causal,
                      const float* lg, const float* lb, bf16* outB) {
    const float* wq = (const float*)d_in[ib + 0];
    const float* bq = (const float*)d_in[ib + 1];
    const float* wk = (const float*)d_in[ib + 2];
    const float* wv = (const float*)d_in[ib + 4];
    const float* bv = (const float*)d_in[ib + 5];
    const float* wo = (const float*)d_in[ib + 6];
    const float* bo = (const float*)d_in[ib + 7];
    const float* wf = (const float*)d_in[ib + 8];
    const float* bfv = (const float*)d_in[ib + 9];

    cast4x4_k<<<dim3(512, 4), dim3(256), 0, stream>>>(
        wq, wk, wv, wo, wqB, wkB, wvB, woB, 2097152 / 4);
    transpose_to_bf16<float><<<dim3(16, 128, 1), dim3(256), 0, stream>>>(wf, wfT, 4096, 512, 0, 0);
    // W2t[e][h*512+f] = sum_g wfT[e][h*512+g] * wo[h][f][g]
    gemmL<64, false, false, true>(stream, 512, 512, 512,
        wfT, 4096, 512, 0, woB, 512, 262144, 0, W2t, 4096, 512, 0, 1, 8, nullptr);
    beff_init_k<<<dim3(2), dim3(256), 0, stream>>>(bfv, beff);
    beff_wf_k<<<dim3(32), dim3(256), 0, stream>>>(bo, wf, beff);
    beff_w2_k<<<dim3(128), dim3(256), 0, stream>>>(bv, W2t, beff);
    // WqkT[h*512+d2][d1] = sum_f wk[h,d2,f] * wq[h,d1,f]
    gemmL<64, false, false, true>(stream, 512, 512, 512,
        wkB, 512, 262144, 0, wqB, 512, 262144, 0, WqkT, 512, 262144, 0, 1, 8, nullptr);
    // W3cat[e][h*512+d] = sum_f W2t[e][h*512+f] * wv[h,d,f]
    gemmL<64, false, false, true>(stream, 512, 512, 512,
        W2t, 4096, 512, 0, wvB, 512, 262144, 0, W3cat, 4096, 512, 0, 1, 8, nullptr);
    wkbq_k<<<dim3(1024), dim3(256), 0, stream>>>(wk, bq, wkbq);
    rank1_v<<<dim3(1024), dim3(256), 0, stream>>>(kvB, wkbq, vbuf);
    transpose_to_bf16<bf16><<<dim3(16, 32, 4), dim3(256), 0, stream>>>(
        kvB, XT, 1024, 512, 524288, 524288);
    // T = qB @ Wqk  [4096, 4096]
    gemmL<128, false, false, true>(stream, 4096, 4096, 512,
        qB, 512, 0, 0, WqkT, 512, 0, 0, T, 4096, 0, 0, 1, 1, nullptr);

    // scores for ALL 32 (h,b): z/4 = head (A col, C hi), z%4 = batch
    gemmL<128, false, false, true>(stream, 1024, 1024, 512,
        T, 4096, 512, 4194304,
        kvB, 512, 0, 524288,
        scores, 1024, 4194304, 1048576, 4, 32, nullptr);
    softmax_rows<<<dim3(8192), dim3(256), 0, stream>>>(scores, vbuf, scale, causal);
    // AX = P @ Xk for all 32
    gemmL<64, false, false, true>(stream, 1024, 512, 1024,
        scores, 1024, 4194304, 1048576,
        XT, 1024, 0, 524288,
        AX, 4096, 512, 4194304, 4, 32, nullptr);
    // out partials = AX @ W3cat^T (split-K = 4)
    gemmL<64, false, false, false>(stream, 4096, 512, 1024,
        AX, 4096, 1024, 0, W3cat, 4096, 1024, 0,
        parts, 512, 2097152, 0, 1, 4, nullptr);
    ln_fused<<<dim3(1024), dim3(256), 0, stream>>>(
        parts, 2097152, 4, beff, resF, resB, lg, lb, outB, nullptr);
  };

  run_attn(2, Xb, Xb, x, nullptr, 1, ln_g[0], ln_b[0], x1b);
  run_attn(12, x1b, Eb, nullptr, x1b, 0, ln_g[1], ln_b[1], x2b);

  // ---- FFN ----
  gemmL<128, true, true, true>(stream, 4096, 2048, 512,
      x2b, 512, 0, 0, fc1T, 512, 0, 0, Hb, 2048, 0, 0, 1, 1, fc1_b);
  gemmL<64, false, false, false>(stream, 4096, 512, 512,
      Hb, 2048, 512, 0, fc2T, 2048, 512, 0, parts, 512, 2097152, 0, 1, 4, nullptr);
  ln_fused<<<dim3(1024), dim3(256), 0, stream>>>(
      parts, 2097152, 4, fc2_b, nullptr, x2b, ln_g[2], ln_b[2], nullptr, (float*)d_out);
}

// Round 7
// 781.407 us; speedup vs baseline: 1.2275x; 1.0203x over previous
//
#include <hip/hip_runtime.h>
#include <hip/hip_bf16.h>

typedef __hip_bfloat16 bf16;
typedef __attribute__((ext_vector_type(8))) __bf16 bf16x8;
typedef __attribute__((ext_vector_type(4))) float f32x4;

typedef const __attribute__((address_space(1))) void cg_void;
typedef __attribute__((address_space(3))) void lds_void;

__device__ inline float b2f(bf16 v) { return __bfloat162float(v); }
__device__ inline bf16 f2b(float v) { return __float2bfloat16(v); }
__device__ inline float ldf(const float* p) { return *p; }
__device__ inline float ldf(const bf16* p) { return __bfloat162float(*p); }

#define BKK 32

template<int N> __device__ __forceinline__ void wait_vm() {
  if constexpr (N == 0) asm volatile("s_waitcnt vmcnt(0)" ::: "memory");
  else if constexpr (N == 3) asm volatile("s_waitcnt vmcnt(3)" ::: "memory");
  else asm volatile("s_waitcnt vmcnt(4)" ::: "memory");
}

// ---------------------------------------------------------------------------
// Batched GEMM: C[z] = A[z] (M x K, row-major lda) * Bt[z]^T (Bt: N x K rows,
// ldb). Per-z offsets: (z/zdiv)*Hi + (z%zdiv)*Lo for A, B, C independently.
// Depth-3 pipelined global_load_lds staging, counted vmcnt (T3+T4 min),
// flat-grid XCD chunking (T1), T2 LDS chunk-XOR swizzle (rule #21: linear LDS
// dest + pre-swizzled SOURCE + same XOR on read; involution chunk^=(row>>1)&3).
// cmode: 0 = none, 1 = causal scores (skip tiles n0>m0), 2 = causal PV
// (clamp K at m0+128; A's upper-triangle cols are exactly zero).
// ---------------------------------------------------------------------------
template<int BN_, bool BIAS, bool RELU, bool OUT_BF16>
__global__ __launch_bounds__(256) void gemm_bt(
    const bf16* __restrict__ A, const bf16* __restrict__ Bt, void* __restrict__ Cout,
    const float* __restrict__ bias,
    int M, int N, int K, int lda, int ldb, int ldc,
    long aHi, long aLo, long bHi, long bLo, long cHi, long cLo, int zdiv, int cmode)
{
  constexpr int NL = (BN_ == 128) ? 4 : 3;   // global_load_lds instrs per tile
  alignas(16) __shared__ bf16 As[3][128 * BKK];
  alignas(16) __shared__ bf16 Bs[3][BN_ * BKK];
  const int t = threadIdx.x;
  const int l = t & 63;
  const int w = t >> 6;

  // T1 flat-grid decode; XCD k owns flat ids [k*total/8, (k+1)*total/8)
  const int gx = gridDim.x;
  const long gxy = (long)gx * gridDim.y;
  long flat = (long)blockIdx.z * gxy + (long)blockIdx.y * gx + blockIdx.x;
  const long total = gxy * gridDim.z;
  if ((total & 7) == 0) flat = (flat & 7) * (total >> 3) + (flat >> 3);
  const int z = (int)(flat / gxy);
  const int rem = (int)(flat % gxy);
  const int m0 = (rem % gx) * 128;
  const int n0 = (rem / gx) * BN_;

  if (cmode == 1 && n0 > m0) return;       // upper-triangle tile: softmax masks it

  const int zq = z / zdiv, zr = z % zdiv;
  A += (long)zq * aHi + (long)zr * aLo;
  Bt += (long)zq * bHi + (long)zr * bLo;
  const long cbase = (long)zq * cHi + (long)zr * cLo;

  constexpr int NJ = BN_ / 32;
  f32x4 acc[4][NJ] = {};

  // staging: thread t owns linear LDS slot t*16B = (row=t>>2, chunk=t&3).
  // T2: that slot must hold global chunk (t&3)^q(row), q(row)=(row>>1)&3=(t>>3)&3.
  const int r0 = t >> 2;
  const int kcs = ((t & 3) ^ ((t >> 3) & 3)) * 8;
  const bf16* aP0 = A + (long)(m0 + r0) * lda + kcs;
  const bf16* aP1 = aP0 + (long)64 * lda;     // row+64: q unchanged ((row>>1)&3)
  const bf16* bP0 = Bt + (long)(n0 + r0) * ldb + kcs;
  const bf16* bP1 = bP0 + (long)64 * ldb;

  const int fr = l & 15;
  const int qa = (fr >> 1) & 3;              // q(row) for this lane's fragment rows
  const int fko = ((l >> 4) ^ qa) << 3;      // swizzled element offset within row
  const int aRow = (w >> 1) * 64 + fr;
  const int bRow = (w & 1) * (BN_ / 2) + fr;

  const int kLim = (cmode == 2) ? (m0 + 128 < K ? m0 + 128 : K) : K;
  const int nt = kLim >> 5;

  auto stage = [&](int tt, int bi) {
    const long kt = (long)tt * BKK;
    __builtin_amdgcn_global_load_lds((cg_void*)(aP0 + kt), (lds_void*)(&As[bi][t * 8]), 16, 0, 0);
    __builtin_amdgcn_global_load_lds((cg_void*)(aP1 + kt), (lds_void*)(&As[bi][(t + 256) * 8]), 16, 0, 0);
    __builtin_amdgcn_global_load_lds((cg_void*)(bP0 + kt), (lds_void*)(&Bs[bi][t * 8]), 16, 0, 0);
    if constexpr (BN_ == 128)
      __builtin_amdgcn_global_load_lds((cg_void*)(bP1 + kt), (lds_void*)(&Bs[bi][(t + 256) * 8]), 16, 0, 0);
  };

  // prologue: tiles 0,1 in flight; wait tile 0 (tile 1 stays outstanding)
  stage(0, 0);
  stage(1, 1);
  wait_vm<NL>();
  __builtin_amdgcn_s_barrier();

  int bi = 0;
  for (int tt = 0; tt < nt; ++tt) {
    if (tt + 2 < nt) stage(tt + 2, bi == 0 ? 2 : bi - 1);
    bf16x8 af[4], bv[NJ];
#pragma unroll
    for (int i = 0; i < 4; ++i)
      af[i] = *(const bf16x8*)(&As[bi][(aRow + i * 16) * BKK + fko]);
#pragma unroll
    for (int j = 0; j < NJ; ++j)
      bv[j] = *(const bf16x8*)(&Bs[bi][(bRow + j * 16) * BKK + fko]);
#pragma unroll
    for (int i = 0; i < 4; ++i)
#pragma unroll
      for (int j = 0; j < NJ; ++j)
        acc[i][j] = __builtin_amdgcn_mfma_f32_16x16x32_bf16(af[i], bv[j], acc[i][j], 0, 0, 0);
    if (tt + 1 < nt) {
      if (tt + 2 < nt) wait_vm<NL>();   // next tile landed; tile t+2 stays in flight
      else wait_vm<0>();                // draining
      __builtin_amdgcn_s_barrier();
    }
    bi = (bi == 2) ? 0 : bi + 1;
  }

  float* cf = (float*)Cout;
  bf16* cb = (bf16*)Cout;
#pragma unroll
  for (int i = 0; i < 4; ++i) {
    const int mb = m0 + (w >> 1) * 64 + i * 16 + ((l >> 4) << 2);
#pragma unroll
    for (int j = 0; j < NJ; ++j) {
      const int nc = n0 + (w & 1) * (BN_ / 2) + j * 16 + fr;
      const float bvv = BIAS ? bias[nc] : 0.f;
#pragma unroll
      for (int r = 0; r < 4; ++r) {
        const int m = mb + r;
        const long off = cbase + (long)m * ldc + nc;
        float vv = acc[i][j][r] + bvv;
        if (RELU) vv = fmaxf(vv, 0.f);
        if (OUT_BF16) cb[off] = f2b(vv);
        else cf[off] = vv;
      }
    }
  }
}

template<int BN_, bool B_, bool R_, bool O_>
static inline void gemmL(hipStream_t st, int M, int N, int K,
                         const bf16* A, int lda, long aHi, long aLo,
                         const bf16* Bt, int ldb, long bHi, long bLo,
                         void* C, int ldc, long cHi, long cLo,
                         int zdiv, int nz, const float* bias, int cmode = 0)
{
  dim3 g(M / 128, N / BN_, nz);
  gemm_bt<BN_, B_, R_, O_><<<g, dim3(256), 0, st>>>(
      A, Bt, C, bias, M, N, K, lda, ldb, ldc, aHi, aLo, bHi, bLo, cHi, cLo, zdiv, cmode);
}

// ---------------------------------------------------------------------------
template<typename ST>
__global__ __launch_bounds__(256) void transpose_to_bf16(
    const ST* __restrict__ in, bf16* __restrict__ out, int R, int C, long sIn, long sOut)
{
  __shared__ bf16 tile[32][33];
  const int z = blockIdx.z;
  in += (long)z * sIn;
  out += (long)z * sOut;
  const int tx = threadIdx.x & 31, ty = threadIdx.x >> 5;
  const int c0 = blockIdx.x * 32, r0 = blockIdx.y * 32;
#pragma unroll
  for (int i = 0; i < 4; ++i)
    tile[ty + i * 8][tx] = f2b(ldf(in + (long)(r0 + ty + i * 8) * C + c0 + tx));
  __syncthreads();
#pragma unroll
  for (int i = 0; i < 4; ++i)
    out[(long)(c0 + ty + i * 8) * R + r0 + tx] = tile[tx][ty + i * 8];
}

__global__ __launch_bounds__(256) void cast4_k(
    const float* __restrict__ in, bf16* __restrict__ out, long n4)
{
  long i = (long)blockIdx.x * 256 + threadIdx.x;
  const long st = (long)gridDim.x * 256;
  for (; i < n4; i += st) {
    const float4 v = ((const float4*)in)[i];
    bf16* o = out + i * 4;
    o[0] = f2b(v.x); o[1] = f2b(v.y); o[2] = f2b(v.z); o[3] = f2b(v.w);
  }
}

// 4 independent f32->bf16 casts in one launch (blockIdx.y selects matrix)
__global__ __launch_bounds__(256) void cast4x4_k(
    const float* __restrict__ p0, const float* __restrict__ p1,
    const float* __restrict__ p2, const float* __restrict__ p3,
    bf16* __restrict__ o0, bf16* __restrict__ o1,
    bf16* __restrict__ o2, bf16* __restrict__ o3, long n4)
{
  const float* in; bf16* out;
  switch (blockIdx.y) {
    case 0: in = p0; out = o0; break;
    case 1: in = p1; out = o1; break;
    case 2: in = p2; out = o2; break;
    default: in = p3; out = o3; break;
  }
  long i = (long)blockIdx.x * 256 + threadIdx.x;
  const long st = (long)gridDim.x * 256;
  for (; i < n4; i += st) {
    const float4 v = ((const float4*)in)[i];
    bf16* o = out + i * 4;
    o[0] = f2b(v.x); o[1] = f2b(v.y); o[2] = f2b(v.z); o[3] = f2b(v.w);
  }
}

__global__ __launch_bounds__(256) void fill_sentinel(float* __restrict__ out, long n)
{
  long i = (long)blockIdx.x * 256 + threadIdx.x;
  const long st = (long)gridDim.x * 256;
  for (; i < n; i += st) out[i] = 1.0e6f;
}

// in-place softmax over 1024-wide rows of bf16 scores; arg = (S + v[t]) * scale
__global__ __launch_bounds__(256) void softmax_rows(
    bf16* __restrict__ S, const float* __restrict__ v, float scale, int causal)
{
  const int r = blockIdx.x * 4 + (threadIdx.x >> 6);
  const int l = threadIdx.x & 63;
  const int zl = r >> 10, s = r & 1023;
  bf16* row = S + (long)r * 1024;
  const float* vp = v + (zl >> 2) * 4096 + (zl & 3) * 1024;
  const int t0 = l * 16;
  bf16x8* rp = (bf16x8*)(row + t0);
  const bf16x8 a0 = rp[0], a1 = rp[1];
  float xx[16];
#pragma unroll
  for (int j = 0; j < 8; ++j) { xx[j] = (float)a0[j]; xx[8 + j] = (float)a1[j]; }
  float mx = -3.4e38f;
#pragma unroll
  for (int k = 0; k < 16; ++k) {
    const int tt = t0 + k;
    float val = (xx[k] + vp[tt]) * scale;
    if (causal && tt > s) val = -3.4e38f;
    xx[k] = val;
    mx = fmaxf(mx, val);
  }
#pragma unroll
  for (int d = 1; d < 64; d <<= 1) mx = fmaxf(mx, __shfl_xor(mx, d));
  float sum = 0.f;
#pragma unroll
  for (int k = 0; k < 16; ++k) {
    const float e = (xx[k] > -1e37f) ? __expf(xx[k] - mx) : 0.f;
    xx[k] = e;
    sum += e;
  }
#pragma unroll
  for (int d = 1; d < 64; d <<= 1) sum += __shfl_xor(sum, d);
  const float inv = 1.f / sum;
  bf16x8 r0v, r1v;
#pragma unroll
  for (int j = 0; j < 8; ++j) {
    r0v[j] = (__bf16)(xx[j] * inv);
    r1v[j] = (__bf16)(xx[8 + j] * inv);
  }
  rp[0] = r0v;
  rp[1] = r1v;
}

// fused: sum split-K partials + beff + residual -> LayerNorm -> bf16/fp32 out
__global__ __launch_bounds__(256) void ln_fused(
    const float* __restrict__ parts, long zstride, int nz,
    const float* __restrict__ beff, const float* __restrict__ resF,
    const bf16* __restrict__ resB, const float* __restrict__ g,
    const float* __restrict__ b, bf16* __restrict__ outB, float* __restrict__ outF)
{
  const int m = blockIdx.x * 4 + (threadIdx.x >> 6);
  const int l = threadIdx.x & 63;
  float vv[8];
  float s = 0.f;
#pragma unroll
  for (int i = 0; i < 8; ++i) {
    const int c = i * 64 + l;
    float acc = beff[c];
    if (resF) acc += resF[(long)m * 512 + c];
    else acc += b2f(resB[(long)m * 512 + c]);
    for (int zz = 0; zz < nz; ++zz) acc += parts[zz * zstride + (long)m * 512 + c];
    vv[i] = acc;
    s += acc;
  }
#pragma unroll
  for (int d = 1; d < 64; d <<= 1) s += __shfl_xor(s, d);
  const float mean = s * (1.f / 512.f);
  float vs = 0.f;
#pragma unroll
  for (int i = 0; i < 8; ++i) { const float dv = vv[i] - mean; vs += dv * dv; }
#pragma unroll
  for (int d = 1; d < 64; d <<= 1) vs += __shfl_xor(vs, d);
  const float rstd = rsqrtf(vs * (1.f / 512.f) + 1e-5f);
#pragma unroll
  for (int i = 0; i < 8; ++i) {
    const int c = i * 64 + l;
    const float y = (vv[i] - mean) * rstd * g[c] + b[c];
    if (outB) outB[(long)m * 512 + c] = f2b(y);
    if (outF) outF[(long)m * 512 + c] = y;
  }
}

// ---- parallel bias-fold kernels ----
__global__ void beff_init_k(const float* __restrict__ bf_, float* __restrict__ beff)
{
  const int e = blockIdx.x * 256 + threadIdx.x;
  if (e < 512) beff[e] = bf_[e];
}

__global__ __launch_bounds__(256) void beff_wf_k(
    const float* __restrict__ bo, const float* __restrict__ wf, float* __restrict__ beff)
{
  const int t = threadIdx.x;
  const int r0 = blockIdx.x * 128;
  float s0 = 0.f, s1 = 0.f;
  for (int r = 0; r < 128; ++r) {
    const float bb = bo[r0 + r];
    const float* row = wf + (long)(r0 + r) * 512;
    s0 += bb * row[t];
    s1 += bb * row[t + 256];
  }
  atomicAdd(&beff[t], s0);
  atomicAdd(&beff[t + 256], s1);
}

__global__ __launch_bounds__(256) void beff_w2_k(
    const float* __restrict__ bv, const bf16* __restrict__ W2t, float* __restrict__ beff)
{
  const int e = blockIdx.x * 4 + (threadIdx.x >> 6);
  const int l = threadIdx.x & 63;
  const bf16* row = W2t + (long)e * 4096;
  float s = 0.f;
#pragma unroll
  for (int j = 0; j < 8; ++j) {
    const int hf = j * 512 + l * 8;
    const bf16x8 wv = *(const bf16x8*)(row + hf);
    const float4 b0 = *(const float4*)(bv + hf);
    const float4 b1 = *(const float4*)(bv + hf + 4);
    s += (float)wv[0] * b0.x + (float)wv[1] * b0.y + (float)wv[2] * b0.z + (float)wv[3] * b0.w;
    s += (float)wv[4] * b1.x + (float)wv[5] * b1.y + (float)wv[6] * b1.z + (float)wv[7] * b1.w;
  }
#pragma unroll
  for (int d = 1; d < 64; d <<= 1) s += __shfl_xor(s, d);
  if (l == 0) atomicAdd(&beff[e], s);
}

__global__ __launch_bounds__(256) void wkbq_k(
    const float* __restrict__ wk, const float* __restrict__ bq, float* __restrict__ o)
{
  const int id = blockIdx.x * 4 + (threadIdx.x >> 6);
  const int l = threadIdx.x & 63;
  const int h = id >> 9, d = id & 511;
  const float* wp = wk + (long)h * 262144 + (long)d * 512 + l * 8;
  const float* bp = bq + h * 512 + l * 8;
  float s = 0.f;
#pragma unroll
  for (int j = 0; j < 2; ++j) {
    const float4 a = *(const float4*)(wp + j * 4);
    const float4 b = *(const float4*)(bp + j * 4);
    s += a.x * b.x + a.y * b.y + a.z * b.z + a.w * b.w;
  }
#pragma unroll
  for (int dd = 1; dd < 64; dd <<= 1) s += __shfl_xor(s, dd);
  if (l == 0) o[id] = s;
}

__global__ __launch_bounds__(256) void rank1_v(
    const bf16* __restrict__ kvB, const float* __restrict__ wkbq, float* __restrict__ v)
{
  const int m = blockIdx.x * 4 + (threadIdx.x >> 6);
  const int l = threadIdx.x & 63;
  const bf16x8 row = *(const bf16x8*)(kvB + (long)m * 512 + l * 8);
  float rf[8];
#pragma unroll
  for (int j = 0; j < 8; ++j) rf[j] = (float)row[j];
  for (int h = 0; h < 8; ++h) {
    const float* wp = wkbq + h * 512 + l * 8;
    float p = 0.f;
#pragma unroll
    for (int j = 0; j < 8; ++j) p += rf[j] * wp[j];
#pragma unroll
    for (int d = 1; d < 64; d <<= 1) p += __shfl_xor(p, d);
    if (l == 0) v[(long)h * 4096 + m] = p;
  }
}

// ---------------------------------------------------------------------------
extern "C" void kernel_launch(void* const* d_in, const int* in_sizes, int n_in,
                              void* d_out, int out_size, void* d_ws, size_t ws_size,
                              hipStream_t stream)
{
  (void)in_sizes; (void)n_in;
  const float* x = (const float*)d_in[0];
  const float* enc = (const float*)d_in[1];
  const float* ln_g[3] = {(const float*)d_in[22], (const float*)d_in[24], (const float*)d_in[26]};
  const float* ln_b[3] = {(const float*)d_in[23], (const float*)d_in[25], (const float*)d_in[27]};
  const float* fc1_w = (const float*)d_in[28];
  const float* fc1_b = (const float*)d_in[29];
  const float* fc2_w = (const float*)d_in[30];
  const float* fc2_b = (const float*)d_in[31];

  const float scale = 0.044194173824159216f;  // 1/sqrt(512)
  char* base = (char*)d_ws;
  const long MB = 1024 * 1024;

  // ---- layout (193 MB; ws is 256 MiB) ----
  bf16* Xb    = (bf16*)(base + 0 * MB);
  bf16* Eb    = (bf16*)(base + 4 * MB);
  bf16* x1b   = (bf16*)(base + 8 * MB);
  bf16* x2b   = (bf16*)(base + 12 * MB);
  bf16* fc1T  = (bf16*)(base + 16 * MB);
  bf16* fc2T  = (bf16*)(base + 18 * MB);
  float* vbuf = (float*)(base + 20 * MB);
  float* wkbq = (float*)(base + 20 * MB + 256 * 1024);
  float* beff = (float*)(base + 20 * MB + 512 * 1024);
  bf16* XT    = (bf16*)(base + 21 * MB);
  bf16* WqkT  = (bf16*)(base + 25 * MB);
  bf16* W3cat = (bf16*)(base + 29 * MB);
  bf16* T     = (bf16*)(base + 33 * MB);     // 32 MB [4096,4096]
  float* parts = (float*)(base + 65 * MB);   // 32 MB [4][4096,512] f32
  bf16* scores = (bf16*)(base + 97 * MB);    // 64 MB [32][1024][1024]
  bf16* AX    = (bf16*)(base + 161 * MB);    // 32 MB [4096,4096]
  // prep scratch + FFN hidden alias the scores region (dead during prep/FFN)
  bf16* wqB   = (bf16*)(base + 97 * MB);
  bf16* wkB   = (bf16*)(base + 101 * MB);
  bf16* wvB   = (bf16*)(base + 105 * MB);
  bf16* woB   = (bf16*)(base + 109 * MB);
  bf16* wfT   = (bf16*)(base + 113 * MB);
  bf16* W2t   = (bf16*)(base + 117 * MB);
  bf16* Hb    = (bf16*)(base + 97 * MB);     // 16 MB [4096,2048]

  if (ws_size < (size_t)(193 * MB)) {
    fill_sentinel<<<dim3(2048), dim3(256), 0, stream>>>((float*)d_out, (long)out_size);
    return;
  }

  // ---- global prep ----
  cast4_k<<<dim3(512), dim3(256), 0, stream>>>(x, Xb, 4096L * 512 / 4);
  cast4_k<<<dim3(512), dim3(256), 0, stream>>>(enc, Eb, 4096L * 512 / 4);
  transpose_to_bf16<float><<<dim3(64, 16, 1), dim3(256), 0, stream>>>(fc1_w, fc1T, 512, 2048, 0, 0);
  transpose_to_bf16<float><<<dim3(16, 64, 1), dim3(256), 0, stream>>>(fc2_w, fc2T, 2048, 512, 0, 0);

  auto run_attn = [&](int ib, const bf16* qB, const bf16* kvB,
                      const float* resF, const bf16* resB, int causal,
                      const float* lg, const float* lb, bf16* outB) {
    const float* wq = (const float*)d_in[ib + 0];
    const float* bq = (const float*)d_in[ib + 1];
    const float* wk = (const float*)d_in[ib + 2];
    const float* wv = (const float*)d_in[ib + 4];
    const float* bv = (const float*)d_in[ib + 5];
    const float* wo = (const float*)d_in[ib + 6];
    const float* bo = (const float*)d_in[ib + 7];
    const float* wf = (const float*)d_in[ib + 8];
    const float* bfv = (const float*)d_in[ib + 9];

    cast4x4_k<<<dim3(512, 4), dim3(256), 0, stream>>>(
        wq, wk, wv, wo, wqB, wkB, wvB, woB, 2097152 / 4);
    transpose_to_bf16<float><<<dim3(16, 128, 1), dim3(256), 0, stream>>>(wf, wfT, 4096, 512, 0, 0);
    // W2t[e][h*512+f] = sum_g wfT[e][h*512+g] * wo[h][f][g]
    gemmL<64, false, false, true>(stream, 512, 512, 512,
        wfT, 4096, 512, 0, woB, 512, 262144, 0, W2t, 4096, 512, 0, 1, 8, nullptr);
    beff_init_k<<<dim3(2), dim3(256), 0, stream>>>(bfv, beff);
    beff_wf_k<<<dim3(32), dim3(256), 0, stream>>>(bo, wf, beff);
    beff_w2_k<<<dim3(128), dim3(256), 0, stream>>>(bv, W2t, beff);
    // WqkT[h*512+d2][d1] = sum_f wk[h,d2,f] * wq[h,d1,f]
    gemmL<64, false, false, true>(stream, 512, 512, 512,
        wkB, 512, 262144, 0, wqB, 512, 262144, 0, WqkT, 512, 262144, 0, 1, 8, nullptr);
    // W3cat[e][h*512+d] = sum_f W2t[e][h*512+f] * wv[h,d,f]
    gemmL<64, false, false, true>(stream, 512, 512, 512,
        W2t, 4096, 512, 0, wvB, 512, 262144, 0, W3cat, 4096, 512, 0, 1, 8, nullptr);
    wkbq_k<<<dim3(1024), dim3(256), 0, stream>>>(wk, bq, wkbq);
    rank1_v<<<dim3(1024), dim3(256), 0, stream>>>(kvB, wkbq, vbuf);
    transpose_to_bf16<bf16><<<dim3(16, 32, 4), dim3(256), 0, stream>>>(
        kvB, XT, 1024, 512, 524288, 524288);
    // T = qB @ Wqk  [4096, 4096]
    gemmL<128, false, false, true>(stream, 4096, 4096, 512,
        qB, 512, 0, 0, WqkT, 512, 0, 0, T, 4096, 0, 0, 1, 1, nullptr);

    // scores for ALL 32 (h,b): z/4 = head (A col, C hi), z%4 = batch
    gemmL<128, false, false, true>(stream, 1024, 1024, 512,
        T, 4096, 512, 4194304,
        kvB, 512, 0, 524288,
        scores, 1024, 4194304, 1048576, 4, 32, nullptr, causal ? 1 : 0);
    softmax_rows<<<dim3(8192), dim3(256), 0, stream>>>(scores, vbuf, scale, causal);
    // AX = P @ Xk for all 32 (causal: P's cols > row are exactly 0 -> clamp K)
    gemmL<64, false, false, true>(stream, 1024, 512, 1024,
        scores, 1024, 4194304, 1048576,
        XT, 1024, 0, 524288,
        AX, 4096, 512, 4194304, 4, 32, nullptr, causal ? 2 : 0);
    // out partials = AX @ W3cat^T (split-K = 4)
    gemmL<64, false, false, false>(stream, 4096, 512, 1024,
        AX, 4096, 1024, 0, W3cat, 4096, 1024, 0,
        parts, 512, 2097152, 0, 1, 4, nullptr);
    ln_fused<<<dim3(1024), dim3(256), 0, stream>>>(
        parts, 2097152, 4, beff, resF, resB, lg, lb, outB, nullptr);
  };

  run_attn(2, Xb, Xb, x, nullptr, 1, ln_g[0], ln_b[0], x1b);
  run_attn(12, x1b, Eb, nullptr, x1b, 0, ln_g[1], ln_b[1], x2b);

  // ---- FFN ----
  gemmL<128, true, true, true>(stream, 4096, 2048, 512,
      x2b, 512, 0, 0, fc1T, 512, 0, 0, Hb, 2048, 0, 0, 1, 1, fc1_b);
  gemmL<64, false, false, false>(stream, 4096, 512, 512,
      Hb, 2048, 512, 0, fc2T, 2048, 512, 0, parts, 512, 2097152, 0, 1, 4, nullptr);
  ln_fused<<<dim3(1024), dim3(256), 0, stream>>>(
      parts, 2097152, 4, fc2_b, nullptr, x2b, ln_g[2], ln_b[2], nullptr, (float*)d_out);
}